// Round 4
// baseline (1352.629 us; speedup 1.0000x reference)
//
#include <hip/hip_runtime.h>

// Problem constants
#define BB 256
#define SS 512
#define DD 128

__device__ __forceinline__ float sigf(float v)  { return 1.0f / (1.0f + __expf(-v)); }
__device__ __forceinline__ float tanhf_(float v){ return 1.0f - 2.0f / (__expf(2.0f * v) + 1.0f); }

typedef _Float16 f16x2 __attribute__((ext_vector_type(2)));

union V4H {
    float4 f4;
    f16x2  h[4];
};

// ---------------------------------------------------------------------------
// Kernel A: precompute additive tables (fold corr/qd/cd embedding matmul parts)
// ---------------------------------------------------------------------------
__global__ void dimkt_tables(const float* __restrict__ E_corr,
                             const float* __restrict__ E_qd,
                             const float* __restrict__ E_cd,
                             const float* __restrict__ W_ki,
                             const float* __restrict__ W_p1,
                             const float* __restrict__ W_p2,
                             const float* __restrict__ b_ki,
                             const float* __restrict__ b_p1,
                             const float* __restrict__ b_p2,
                             float* __restrict__ Ck, float* __restrict__ Cp1,
                             float* __restrict__ Cp2, float* __restrict__ Qk,
                             float* __restrict__ Cdk)
{
    __shared__ float e[128];
    const int r = blockIdx.x;
    const int j = threadIdx.x;
    const float *emb, *W, *bias;
    float* op;
    if (r < 2)        { emb = E_corr + r * 128;        W = W_ki + 128 * 128; bias = b_ki;    op = Ck  + r * 128; }
    else if (r < 4)   { emb = E_corr + (r - 2) * 128;  W = W_p1 + 128 * 128; bias = b_p1;    op = Cp1 + (r - 2) * 128; }
    else if (r < 6)   { emb = E_corr + (r - 4) * 128;  W = W_p2 + 128 * 128; bias = b_p2;    op = Cp2 + (r - 4) * 128; }
    else if (r < 107) { emb = E_qd   + (r - 6) * 128;  W = W_ki + 256 * 128; bias = nullptr; op = Qk  + (r - 6) * 128; }
    else              { emb = E_cd   + (r - 107) * 128; W = W_ki + 384 * 128; bias = nullptr; op = Cdk + (r - 107) * 128; }
    e[j] = emb[j];
    __syncthreads();
    float acc = bias ? bias[j] : 0.0f;
#pragma unroll 8
    for (int i = 0; i < 128; ++i) acc = fmaf(e[i], W[i * 128 + j], acc);
    op[j] = acc;
}

// ---------------------------------------------------------------------------
// Kernel B: x = concat(E_q[q], E_c[c], E_qd[qd], E_cd[cd]) @ Wx + bx
//   (unchanged — fp32 LDS-tiled GEMM; MFMA candidate next round)
// ---------------------------------------------------------------------------
#define AP 134

__global__ __launch_bounds__(256, 2) void dimkt_xgemm(
    const int* __restrict__ q_seq, const int* __restrict__ c_seq,
    const int* __restrict__ qd_seq, const int* __restrict__ cd_seq,
    const float* __restrict__ E_q, const float* __restrict__ E_c,
    const float* __restrict__ E_qd, const float* __restrict__ E_cd,
    const float* __restrict__ Wx, const float* __restrict__ bx,
    float* __restrict__ xout)
{
    __shared__ float As[128 * AP];
    __shared__ float Bs[128 * 128];
    const int tid = threadIdx.x;
    const int ty = tid >> 4;
    const int tx = tid & 15;
    const int m0 = blockIdx.x * 128;

    const int*   seqs[4] = { q_seq, c_seq, qd_seq, cd_seq };
    const float* tabs[4] = { E_q,   E_c,   E_qd,   E_cd  };

    float acc[8][8];
#pragma unroll
    for (int r = 0; r < 8; ++r)
#pragma unroll
        for (int c = 0; c < 8; ++c) acc[r][c] = 0.0f;

#pragma unroll 1
    for (int s = 0; s < 4; ++s) {
        __syncthreads();
        const int*   sq = seqs[s];
        const float* tb = tabs[s];
        for (int i = tid; i < 128 * 64; i += 256) {
            int row = i >> 6;
            int c2  = (i & 63) << 1;
            int e   = sq[m0 + row];
            float2 v = *(const float2*)&tb[e * 128 + c2];
            *(float2*)&As[row * AP + c2] = v;
        }
        for (int i = tid; i < 128 * 32; i += 256) {
            int k  = i >> 5;
            int c4 = (i & 31) << 2;
            *(float4*)&Bs[k * 128 + c4] = *(const float4*)&Wx[(s * 128 + k) * 128 + c4];
        }
        __syncthreads();
#pragma unroll 4
        for (int k = 0; k < 128; ++k) {
            float a[8];
#pragma unroll
            for (int r = 0; r < 8; ++r) a[r] = As[(ty * 8 + r) * AP + k];
            float4 b0 = *(const float4*)&Bs[k * 128 + tx * 8];
            float4 b1 = *(const float4*)&Bs[k * 128 + tx * 8 + 4];
            float bb[8] = { b0.x, b0.y, b0.z, b0.w, b1.x, b1.y, b1.z, b1.w };
#pragma unroll
            for (int r = 0; r < 8; ++r)
#pragma unroll
                for (int c = 0; c < 8; ++c)
                    acc[r][c] = fmaf(a[r], bb[c], acc[r][c]);
        }
    }

    float4 bx0 = *(const float4*)&bx[tx * 8];
    float4 bx1 = *(const float4*)&bx[tx * 8 + 4];
    float bxa[8] = { bx0.x, bx0.y, bx0.z, bx0.w, bx1.x, bx1.y, bx1.z, bx1.w };
#pragma unroll
    for (int r = 0; r < 8; ++r) {
        int row = m0 + ty * 8 + r;
        float4 o0 = make_float4(acc[r][0] + bxa[0], acc[r][1] + bxa[1],
                                acc[r][2] + bxa[2], acc[r][3] + bxa[3]);
        float4 o1 = make_float4(acc[r][4] + bxa[4], acc[r][5] + bxa[5],
                                acc[r][6] + bxa[6], acc[r][7] + bxa[7]);
        *(float4*)&xout[row * 128 + tx * 8]     = o0;
        *(float4*)&xout[row * 128 + tx * 8 + 4] = o1;
    }
}

// ---------------------------------------------------------------------------
// Kernel C: sequential scan, v3.
//   1024 threads (16 waves, 4/SIMD). Wave w owns output cols [8w, 8w+8);
//   lane (r=ln>>3, jc=ln&7) owns rows [16r,16r+16) of col j=8w+jc.
//   Weights packed f16x2 along K: 8 x f16x2 per matrix x 5 = 40 VGPRs/thread
//   (vs 160 fp32 in r3, which the compiler kept shuffling via AGPRs:
//   VGPR_Count=124 < 160, VALU 2x the FMA floor). v_dot2_f32_f16 halves the
//   math ops; fp32 accumulation and fp32 h-state preserved.
//   Row-group reduction = 3x shfl_xor (masks 8/16/32) -> no LDS partials,
//   2 barriers/step (vs 4).
// ---------------------------------------------------------------------------
__global__ __launch_bounds__(1024) void dimkt_scan(
    const float* __restrict__ x,
    const int* __restrict__ corr_seq, const int* __restrict__ qd_seq,
    const int* __restrict__ cd_seq,
    const float* __restrict__ W_s1, const float* __restrict__ b_s1,
    const float* __restrict__ W_s2, const float* __restrict__ b_s2,
    const float* __restrict__ W_p1, const float* __restrict__ W_p2,
    const float* __restrict__ W_ki,
    const float* __restrict__ Ck, const float* __restrict__ Cp1,
    const float* __restrict__ Cp2, const float* __restrict__ Qk,
    const float* __restrict__ Cdk,
    const float* __restrict__ h0, float* __restrict__ out)
{
    __shared__ __align__(16) _Float16 d_h[128];
    __shared__ __align__(16) _Float16 h_h[128];
    __shared__ __align__(16) _Float16 s_h[128];
    __shared__ float ypart[16];

    const int tid  = threadIdx.x;
    const int b    = blockIdx.x;
    const int w    = tid >> 6;       // wave id 0..15: cols [8w, 8w+8)
    const int ln   = tid & 63;
    const int r    = ln >> 3;        // row group 0..7: rows [16r, 16r+16)
    const int jc   = ln & 7;
    const int j    = w * 8 + jc;     // output column
    const int R    = r * 16;         // first row of this thread's K slice
    const int base = b * SS;

    // --- register-resident f16x2 weights (40 regs), fully unrolled ----------
    f16x2 w1[8], w2[8], wk[8], wp1[8], wp2[8];
#pragma unroll
    for (int m = 0; m < 8; ++m) {
        const int i0 = (R + 2 * m) * 128 + j;
        f16x2 t;
        t.x = (_Float16)W_s1[i0]; t.y = (_Float16)W_s1[i0 + 128]; w1[m]  = t;
        t.x = (_Float16)W_s2[i0]; t.y = (_Float16)W_s2[i0 + 128]; w2[m]  = t;
        t.x = (_Float16)W_ki[i0]; t.y = (_Float16)W_ki[i0 + 128]; wk[m]  = t;
        t.x = (_Float16)W_p1[i0]; t.y = (_Float16)W_p1[i0 + 128]; wp1[m] = t;
        t.x = (_Float16)W_p2[i0]; t.y = (_Float16)W_p2[i0 + 128]; wp2[m] = t;
    }

    const float bs1 = b_s1[j];
    const float bs2 = b_s2[j];
    float h = h0[b * 128 + j];       // redundant across the 8 r-lanes of col j

    {
        float x0 = x[(size_t)base * 128 + j];
        if (r == 0) {
            h_h[j] = (_Float16)h;
            d_h[j] = (_Float16)(x0 - h);
        }
    }
    // step-0 tables
    int c0 = corr_seq[base], q0 = qd_seq[base], e0 = cd_seq[base];
    float ck  = Ck [c0 * 128 + j];
    float qk  = Qk [q0 * 128 + j];
    float cdk = Cdk[e0 * 128 + j];
    float cp1 = Cp1[c0 * 128 + j];
    float cp2 = Cp2[c0 * 128 + j];
    __syncthreads();

    for (int t = 0; t < 511; ++t) {
        // ---- phase 1: a1 = d@Ws1, a2 = d@Ws2, kg = h@Wki_h -----------------
        // prefetch x_{t+1} and next-step tables (consumed after B1 / next iter)
        const int n1 = base + t + 1;
        float xn = x[(size_t)n1 * 128 + j];
        int c1 = corr_seq[n1], q1 = qd_seq[n1], e1 = cd_seq[n1];
        float nck  = Ck [c1 * 128 + j];
        float nqk  = Qk [q1 * 128 + j];
        float ncdk = Cdk[e1 * 128 + j];
        float ncp1 = Cp1[c1 * 128 + j];
        float ncp2 = Cp2[c1 * 128 + j];

        // drain y_{t-1} (wave 15 side-job; ypart written before last barrier)
        if (w == 15 && ln < 16 && t > 0) {
            float yp = ypart[ln];
            yp += __shfl_xor(yp, 1); yp += __shfl_xor(yp, 2);
            yp += __shfl_xor(yp, 4); yp += __shfl_xor(yp, 8);
            if (ln == 0) out[base + t - 1] = sigf(yp);
        }

        V4H da, db, ha, hb;
        da.f4 = *(const float4*)&d_h[R];
        db.f4 = *(const float4*)&d_h[R + 8];
        ha.f4 = *(const float4*)&h_h[R];
        hb.f4 = *(const float4*)&h_h[R + 8];
        float a1 = 0.f, a2 = 0.f, kg = 0.f;
#pragma unroll
        for (int m = 0; m < 4; ++m) {
            a1 = __builtin_amdgcn_fdot2(da.h[m], w1[m], a1, false);
            a2 = __builtin_amdgcn_fdot2(da.h[m], w2[m], a2, false);
            kg = __builtin_amdgcn_fdot2(ha.h[m], wk[m], kg, false);
        }
#pragma unroll
        for (int m = 0; m < 4; ++m) {
            a1 = __builtin_amdgcn_fdot2(db.h[m], w1[m + 4], a1, false);
            a2 = __builtin_amdgcn_fdot2(db.h[m], w2[m + 4], a2, false);
            kg = __builtin_amdgcn_fdot2(hb.h[m], wk[m + 4], kg, false);
        }
        // reduce over the 8 row-groups (lane bits 3..5)
        a1 += __shfl_xor(a1, 8);  a2 += __shfl_xor(a2, 8);  kg += __shfl_xor(kg, 8);
        a1 += __shfl_xor(a1, 16); a2 += __shfl_xor(a2, 16); kg += __shfl_xor(kg, 16);
        a1 += __shfl_xor(a1, 32); a2 += __shfl_xor(a2, 32); kg += __shfl_xor(kg, 32);

        float sdf = sigf(a1 + bs1) * tanhf_(a2 + bs2);
        float g   = sigf(kg + ck + qk + cdk);
        if (r == 0) s_h[j] = (_Float16)sdf;
        __syncthreads();   // B1

        // ---- phase 2: p1 = sdf@Wp1_h, p2 = sdf@Wp2_h; h update -------------
        V4H sa, sb;
        sa.f4 = *(const float4*)&s_h[R];
        sb.f4 = *(const float4*)&s_h[R + 8];
        float p1 = 0.f, p2 = 0.f;
#pragma unroll
        for (int m = 0; m < 4; ++m) {
            p1 = __builtin_amdgcn_fdot2(sa.h[m], wp1[m], p1, false);
            p2 = __builtin_amdgcn_fdot2(sa.h[m], wp2[m], p2, false);
        }
#pragma unroll
        for (int m = 0; m < 4; ++m) {
            p1 = __builtin_amdgcn_fdot2(sb.h[m], wp1[m + 4], p1, false);
            p2 = __builtin_amdgcn_fdot2(sb.h[m], wp2[m + 4], p2, false);
        }
        p1 += __shfl_xor(p1, 8);  p2 += __shfl_xor(p2, 8);
        p1 += __shfl_xor(p1, 16); p2 += __shfl_xor(p2, 16);
        p1 += __shfl_xor(p1, 32); p2 += __shfl_xor(p2, 32);

        float pka = sigf(p1 + cp1) * tanhf_(p2 + cp2);
        float hn  = g * h + (1.f - g) * pka;
        float dn  = xn - hn;       // d for step t+1
        float pr  = xn * hn;       // y_t product
        if (r == 0) { h_h[j] = (_Float16)hn; d_h[j] = (_Float16)dn; }

        // y partial: sum over this wave's 8 cols (lane bits 0..2)
        pr += __shfl_xor(pr, 1); pr += __shfl_xor(pr, 2); pr += __shfl_xor(pr, 4);
        if (ln == 0) ypart[w] = pr;

        h = hn;
        ck = nck; qk = nqk; cdk = ncdk; cp1 = ncp1; cp2 = ncp2;
        __syncthreads();   // B2
    }

    // ---- epilogue: y_510; y[:,511] = 0 --------------------------------------
    if (w == 15 && ln < 16) {
        float yp = ypart[ln];
        yp += __shfl_xor(yp, 1); yp += __shfl_xor(yp, 2);
        yp += __shfl_xor(yp, 4); yp += __shfl_xor(yp, 8);
        if (ln == 0) out[base + 510] = sigf(yp);
    }
    if (tid == 0) out[base + 511] = 0.0f;
}

// ---------------------------------------------------------------------------
extern "C" void kernel_launch(void* const* d_in, const int* in_sizes, int n_in,
                              void* d_out, int out_size, void* d_ws, size_t ws_size,
                              hipStream_t stream) {
    const int*   q_seq    = (const int*)d_in[0];
    const int*   c_seq    = (const int*)d_in[1];
    const int*   qd_seq   = (const int*)d_in[2];
    const int*   cd_seq   = (const int*)d_in[3];
    const int*   corr_seq = (const int*)d_in[4];
    const float* E_q    = (const float*)d_in[5];
    const float* E_c    = (const float*)d_in[6];
    const float* E_qd   = (const float*)d_in[7];
    const float* E_cd   = (const float*)d_in[8];
    const float* E_corr = (const float*)d_in[9];
    const float* Wx     = (const float*)d_in[10];
    const float* bx     = (const float*)d_in[11];
    const float* W_s1   = (const float*)d_in[12];
    const float* b_s1   = (const float*)d_in[13];
    const float* W_s2   = (const float*)d_in[14];
    const float* b_s2   = (const float*)d_in[15];
    const float* W_p1   = (const float*)d_in[16];
    const float* b_p1   = (const float*)d_in[17];
    const float* W_p2   = (const float*)d_in[18];
    const float* b_p2   = (const float*)d_in[19];
    const float* W_ki   = (const float*)d_in[20];
    const float* b_ki   = (const float*)d_in[21];
    const float* h0     = (const float*)d_in[22];
    float* out = (float*)d_out;

    float* xbuf = (float*)d_ws;
    float* Ck   = xbuf + (size_t)BB * SS * DD;
    float* Cp1  = Ck  + 256;
    float* Cp2  = Cp1 + 256;
    float* Qk   = Cp2 + 256;
    float* Cdk  = Qk  + 101 * 128;

    dimkt_tables<<<208, 128, 0, stream>>>(E_corr, E_qd, E_cd, W_ki, W_p1, W_p2,
                                          b_ki, b_p1, b_p2, Ck, Cp1, Cp2, Qk, Cdk);

    dimkt_xgemm<<<(BB * SS) / 128, 256, 0, stream>>>(q_seq, c_seq, qd_seq, cd_seq,
                                                     E_q, E_c, E_qd, E_cd, Wx, bx, xbuf);

    dimkt_scan<<<BB, 1024, 0, stream>>>(xbuf, corr_seq, qd_seq, cd_seq,
                                        W_s1, b_s1, W_s2, b_s2, W_p1, W_p2, W_ki,
                                        Ck, Cp1, Cp2, Qk, Cdk, h0, out);
}

// Round 5
// 1167.239 us; speedup vs baseline: 1.1588x; 1.1588x over previous
//
#include <hip/hip_runtime.h>

// Problem constants
#define BB 256
#define SS 512
#define DD 128

__device__ __forceinline__ float sigf(float v)  { return 1.0f / (1.0f + __expf(-v)); }
__device__ __forceinline__ float tanhf_(float v){ return 1.0f - 2.0f / (__expf(2.0f * v) + 1.0f); }

typedef _Float16 f16x2 __attribute__((ext_vector_type(2)));

union V4H {
    float4 f4;
    f16x2  h[4];
};

// ---------------------------------------------------------------------------
// Kernel A: precompute additive tables (fold corr/qd/cd embedding matmul parts)
// ---------------------------------------------------------------------------
__global__ void dimkt_tables(const float* __restrict__ E_corr,
                             const float* __restrict__ E_qd,
                             const float* __restrict__ E_cd,
                             const float* __restrict__ W_ki,
                             const float* __restrict__ W_p1,
                             const float* __restrict__ W_p2,
                             const float* __restrict__ b_ki,
                             const float* __restrict__ b_p1,
                             const float* __restrict__ b_p2,
                             float* __restrict__ Ck, float* __restrict__ Cp1,
                             float* __restrict__ Cp2, float* __restrict__ Qk,
                             float* __restrict__ Cdk)
{
    __shared__ float e[128];
    const int r = blockIdx.x;
    const int j = threadIdx.x;
    const float *emb, *W, *bias;
    float* op;
    if (r < 2)        { emb = E_corr + r * 128;        W = W_ki + 128 * 128; bias = b_ki;    op = Ck  + r * 128; }
    else if (r < 4)   { emb = E_corr + (r - 2) * 128;  W = W_p1 + 128 * 128; bias = b_p1;    op = Cp1 + (r - 2) * 128; }
    else if (r < 6)   { emb = E_corr + (r - 4) * 128;  W = W_p2 + 128 * 128; bias = b_p2;    op = Cp2 + (r - 4) * 128; }
    else if (r < 107) { emb = E_qd   + (r - 6) * 128;  W = W_ki + 256 * 128; bias = nullptr; op = Qk  + (r - 6) * 128; }
    else              { emb = E_cd   + (r - 107) * 128; W = W_ki + 384 * 128; bias = nullptr; op = Cdk + (r - 107) * 128; }
    e[j] = emb[j];
    __syncthreads();
    float acc = bias ? bias[j] : 0.0f;
#pragma unroll 8
    for (int i = 0; i < 128; ++i) acc = fmaf(e[i], W[i * 128 + j], acc);
    op[j] = acc;
}

// ---------------------------------------------------------------------------
// Kernel B: x = concat(E_q[q], E_c[c], E_qd[qd], E_cd[cd]) @ Wx + bx
//   (unchanged — fp32 LDS-tiled GEMM; MFMA candidate next round)
// ---------------------------------------------------------------------------
#define AP 134

__global__ __launch_bounds__(256, 2) void dimkt_xgemm(
    const int* __restrict__ q_seq, const int* __restrict__ c_seq,
    const int* __restrict__ qd_seq, const int* __restrict__ cd_seq,
    const float* __restrict__ E_q, const float* __restrict__ E_c,
    const float* __restrict__ E_qd, const float* __restrict__ E_cd,
    const float* __restrict__ Wx, const float* __restrict__ bx,
    float* __restrict__ xout)
{
    __shared__ float As[128 * AP];
    __shared__ float Bs[128 * 128];
    const int tid = threadIdx.x;
    const int ty = tid >> 4;
    const int tx = tid & 15;
    const int m0 = blockIdx.x * 128;

    const int*   seqs[4] = { q_seq, c_seq, qd_seq, cd_seq };
    const float* tabs[4] = { E_q,   E_c,   E_qd,   E_cd  };

    float acc[8][8];
#pragma unroll
    for (int r = 0; r < 8; ++r)
#pragma unroll
        for (int c = 0; c < 8; ++c) acc[r][c] = 0.0f;

#pragma unroll 1
    for (int s = 0; s < 4; ++s) {
        __syncthreads();
        const int*   sq = seqs[s];
        const float* tb = tabs[s];
        for (int i = tid; i < 128 * 64; i += 256) {
            int row = i >> 6;
            int c2  = (i & 63) << 1;
            int e   = sq[m0 + row];
            float2 v = *(const float2*)&tb[e * 128 + c2];
            *(float2*)&As[row * AP + c2] = v;
        }
        for (int i = tid; i < 128 * 32; i += 256) {
            int k  = i >> 5;
            int c4 = (i & 31) << 2;
            *(float4*)&Bs[k * 128 + c4] = *(const float4*)&Wx[(s * 128 + k) * 128 + c4];
        }
        __syncthreads();
#pragma unroll 4
        for (int k = 0; k < 128; ++k) {
            float a[8];
#pragma unroll
            for (int r = 0; r < 8; ++r) a[r] = As[(ty * 8 + r) * AP + k];
            float4 b0 = *(const float4*)&Bs[k * 128 + tx * 8];
            float4 b1 = *(const float4*)&Bs[k * 128 + tx * 8 + 4];
            float bb[8] = { b0.x, b0.y, b0.z, b0.w, b1.x, b1.y, b1.z, b1.w };
#pragma unroll
            for (int r = 0; r < 8; ++r)
#pragma unroll
                for (int c = 0; c < 8; ++c)
                    acc[r][c] = fmaf(a[r], bb[c], acc[r][c]);
        }
    }

    float4 bx0 = *(const float4*)&bx[tx * 8];
    float4 bx1 = *(const float4*)&bx[tx * 8 + 4];
    float bxa[8] = { bx0.x, bx0.y, bx0.z, bx0.w, bx1.x, bx1.y, bx1.z, bx1.w };
#pragma unroll
    for (int r = 0; r < 8; ++r) {
        int row = m0 + ty * 8 + r;
        float4 o0 = make_float4(acc[r][0] + bxa[0], acc[r][1] + bxa[1],
                                acc[r][2] + bxa[2], acc[r][3] + bxa[3]);
        float4 o1 = make_float4(acc[r][4] + bxa[4], acc[r][5] + bxa[5],
                                acc[r][6] + bxa[6], acc[r][7] + bxa[7]);
        *(float4*)&xout[row * 128 + tx * 8]     = o0;
        *(float4*)&xout[row * 128 + tx * 8 + 4] = o1;
    }
}

// ---------------------------------------------------------------------------
// Kernel C: sequential scan, v4.
//   512 threads (8 waves). Wave wv owns cols [16wv,16wv+16); lane (r=ln>>4,
//   jc=ln&15) owns rows [32r,32r+32) of col j. f16x2 weights: 16x5 = 80
//   VGPRs/thread. Row-group reduce = 2 shfl_xor (16,32). Nonlinearities only
//   on r==0 lanes (r4 lesson: redundant transcendentals across 16 waves cost
//   ~384cy/step). Prefetch specialization (r4 lesson: 144 VMEM instr/step ->
//   ~7): wave0-4 load one table row each (double-buffered LDS, issue-early /
//   write-late), wave5 loads x two steps ahead, wave6 drains y. 2 barriers/step.
// ---------------------------------------------------------------------------
__global__ __launch_bounds__(512) void dimkt_scan(
    const float* __restrict__ x,
    const int* __restrict__ corr_seq, const int* __restrict__ qd_seq,
    const int* __restrict__ cd_seq,
    const float* __restrict__ W_s1, const float* __restrict__ b_s1,
    const float* __restrict__ W_s2, const float* __restrict__ b_s2,
    const float* __restrict__ W_p1, const float* __restrict__ W_p2,
    const float* __restrict__ W_ki,
    const float* __restrict__ Ck, const float* __restrict__ Cp1,
    const float* __restrict__ Cp2, const float* __restrict__ Qk,
    const float* __restrict__ Cdk,
    const float* __restrict__ h0, float* __restrict__ out)
{
    __shared__ __align__(16) _Float16 d_h[128];
    __shared__ __align__(16) _Float16 h_h[128];
    __shared__ __align__(16) _Float16 s_h[128];
    __shared__ float tabCk[2][128], tabQk[2][128], tabCdk[2][128];
    __shared__ float tabP1[2][128], tabP2[2][128];
    __shared__ float xn_f[2][128];
    __shared__ float ypart[8];

    const int tid  = threadIdx.x;
    const int b    = blockIdx.x;
    const int wv   = tid >> 6;       // wave id 0..7: cols [16wv, 16wv+16)
    const int ln   = tid & 63;
    const int r    = ln >> 4;        // row group 0..3: rows [32r, 32r+32)
    const int jc   = ln & 15;
    const int j    = wv * 16 + jc;   // output column
    const int R    = r * 32;         // first row of this thread's K slice
    const int base = b * SS;

    // --- register-resident f16x2 weights (80 regs), fully unrolled ----------
    f16x2 w1[16], w2[16], wk[16], wp1[16], wp2[16];
#pragma unroll
    for (int m = 0; m < 16; ++m) {
        const int i0 = (R + 2 * m) * 128 + j;
        f16x2 tt;
        tt.x = (_Float16)W_s1[i0]; tt.y = (_Float16)W_s1[i0 + 128]; w1[m]  = tt;
        tt.x = (_Float16)W_s2[i0]; tt.y = (_Float16)W_s2[i0 + 128]; w2[m]  = tt;
        tt.x = (_Float16)W_ki[i0]; tt.y = (_Float16)W_ki[i0 + 128]; wk[m]  = tt;
        tt.x = (_Float16)W_p1[i0]; tt.y = (_Float16)W_p1[i0 + 128]; wp1[m] = tt;
        tt.x = (_Float16)W_p2[i0]; tt.y = (_Float16)W_p2[i0 + 128]; wp2[m] = tt;
    }

    // --- prologue ------------------------------------------------------------
    float bs1 = 0.f, bs2 = 0.f, h = 0.f;
    if (r == 0) {
        bs1 = b_s1[j];
        bs2 = b_s2[j];
        h = h0[b * 128 + j];
        float x0 = x[(size_t)base * 128 + j];
        h_h[j] = (_Float16)h;
        d_h[j] = (_Float16)(x0 - h);
    }
    // step-0 tables (waves 0-4) and X(1) (wave 5)
    float2 pfNew = make_float2(0.f, 0.f);
    {
        if (wv == 0)      pfNew = *(const float2*)&Ck [corr_seq[base] * 128 + 2 * ln];
        else if (wv == 1) pfNew = *(const float2*)&Qk [qd_seq[base]   * 128 + 2 * ln];
        else if (wv == 2) pfNew = *(const float2*)&Cdk[cd_seq[base]   * 128 + 2 * ln];
        else if (wv == 3) pfNew = *(const float2*)&Cp1[corr_seq[base] * 128 + 2 * ln];
        else if (wv == 4) pfNew = *(const float2*)&Cp2[corr_seq[base] * 128 + 2 * ln];
        else if (wv == 5) pfNew = *(const float2*)&x[(size_t)(base + 1) * 128 + 2 * ln];
        if (wv == 0)      *(float2*)&tabCk [0][2 * ln] = pfNew;
        else if (wv == 1) *(float2*)&tabQk [0][2 * ln] = pfNew;
        else if (wv == 2) *(float2*)&tabCdk[0][2 * ln] = pfNew;
        else if (wv == 3) *(float2*)&tabP1 [0][2 * ln] = pfNew;
        else if (wv == 4) *(float2*)&tabP2 [0][2 * ln] = pfNew;
    }
    float2 pfHold = pfNew;   // wave5: holds X(t+1) across the iteration
    __syncthreads();

    for (int t = 0; t < 511; ++t) {
        const int buf = t & 1;
        // ---- issue prefetches for step t+1 (wave-specialized) --------------
        const int n1 = base + t + 1;
        if (wv == 0)      pfNew = *(const float2*)&Ck [corr_seq[n1] * 128 + 2 * ln];
        else if (wv == 1) pfNew = *(const float2*)&Qk [qd_seq[n1]   * 128 + 2 * ln];
        else if (wv == 2) pfNew = *(const float2*)&Cdk[cd_seq[n1]   * 128 + 2 * ln];
        else if (wv == 3) pfNew = *(const float2*)&Cp1[corr_seq[n1] * 128 + 2 * ln];
        else if (wv == 4) pfNew = *(const float2*)&Cp2[corr_seq[n1] * 128 + 2 * ln];
        else if (wv == 5) {
            int xp = t + 2; if (xp > 511) xp = 511;
            pfNew = *(const float2*)&x[(size_t)(base + xp) * 128 + 2 * ln];
        }

        // ---- wave6 side-job: emit y_{t-1} (reads ypart from step t-1) ------
        if (wv == 6 && ln < 8 && t > 0) {
            float yp = ypart[ln];
            yp += __shfl_xor(yp, 1); yp += __shfl_xor(yp, 2); yp += __shfl_xor(yp, 4);
            if (ln == 0) out[base + t - 1] = sigf(yp);
        }

        // ---- phase 1: a1 = d@Ws1, a2 = d@Ws2, kg = h@Wki_h -----------------
        V4H d0, d1, d2, d3, g0, g1, g2, g3;
        d0.f4 = *(const float4*)&d_h[R];
        d1.f4 = *(const float4*)&d_h[R + 8];
        d2.f4 = *(const float4*)&d_h[R + 16];
        d3.f4 = *(const float4*)&d_h[R + 24];
        g0.f4 = *(const float4*)&h_h[R];
        g1.f4 = *(const float4*)&h_h[R + 8];
        g2.f4 = *(const float4*)&h_h[R + 16];
        g3.f4 = *(const float4*)&h_h[R + 24];
        float a1a = 0.f, a1b = 0.f, a2a = 0.f, a2b = 0.f, kga = 0.f, kgb = 0.f;
#pragma unroll
        for (int m = 0; m < 4; ++m) {
            a1a = __builtin_amdgcn_fdot2(d0.h[m], w1[m],      a1a, false);
            a1b = __builtin_amdgcn_fdot2(d1.h[m], w1[m + 4],  a1b, false);
            a2a = __builtin_amdgcn_fdot2(d0.h[m], w2[m],      a2a, false);
            a2b = __builtin_amdgcn_fdot2(d1.h[m], w2[m + 4],  a2b, false);
            kga = __builtin_amdgcn_fdot2(g0.h[m], wk[m],      kga, false);
            kgb = __builtin_amdgcn_fdot2(g1.h[m], wk[m + 4],  kgb, false);
            a1a = __builtin_amdgcn_fdot2(d2.h[m], w1[m + 8],  a1a, false);
            a1b = __builtin_amdgcn_fdot2(d3.h[m], w1[m + 12], a1b, false);
            a2a = __builtin_amdgcn_fdot2(d2.h[m], w2[m + 8],  a2a, false);
            a2b = __builtin_amdgcn_fdot2(d3.h[m], w2[m + 12], a2b, false);
            kga = __builtin_amdgcn_fdot2(g2.h[m], wk[m + 8],  kga, false);
            kgb = __builtin_amdgcn_fdot2(g3.h[m], wk[m + 12], kgb, false);
        }
        float a1 = a1a + a1b, a2 = a2a + a2b, kg = kga + kgb;
        a1 += __shfl_xor(a1, 16); a2 += __shfl_xor(a2, 16); kg += __shfl_xor(kg, 16);
        a1 += __shfl_xor(a1, 32); a2 += __shfl_xor(a2, 32); kg += __shfl_xor(kg, 32);

        float g = 0.f;
        if (r == 0) {
            float ktab = tabCk[buf][j] + tabQk[buf][j] + tabCdk[buf][j];
            float sdf  = sigf(a1 + bs1) * tanhf_(a2 + bs2);
            g = sigf(kg + ktab);
            s_h[j] = (_Float16)sdf;
        }
        // wave5: commit X(t+1) to LDS (loaded last iteration; consumed phase 2)
        if (wv == 5) *(float2*)&xn_f[buf][2 * ln] = pfHold;
        __syncthreads();   // B1

        // ---- phase 2: p1 = sdf@Wp1_h, p2 = sdf@Wp2_h; h update -------------
        V4H s0, s1, s2, s3;
        s0.f4 = *(const float4*)&s_h[R];
        s1.f4 = *(const float4*)&s_h[R + 8];
        s2.f4 = *(const float4*)&s_h[R + 16];
        s3.f4 = *(const float4*)&s_h[R + 24];
        float p1a = 0.f, p1b = 0.f, p2a = 0.f, p2b = 0.f;
#pragma unroll
        for (int m = 0; m < 4; ++m) {
            p1a = __builtin_amdgcn_fdot2(s0.h[m], wp1[m],      p1a, false);
            p1b = __builtin_amdgcn_fdot2(s1.h[m], wp1[m + 4],  p1b, false);
            p2a = __builtin_amdgcn_fdot2(s0.h[m], wp2[m],      p2a, false);
            p2b = __builtin_amdgcn_fdot2(s1.h[m], wp2[m + 4],  p2b, false);
            p1a = __builtin_amdgcn_fdot2(s2.h[m], wp1[m + 8],  p1a, false);
            p1b = __builtin_amdgcn_fdot2(s3.h[m], wp1[m + 12], p1b, false);
            p2a = __builtin_amdgcn_fdot2(s2.h[m], wp2[m + 8],  p2a, false);
            p2b = __builtin_amdgcn_fdot2(s3.h[m], wp2[m + 12], p2b, false);
        }
        float p1 = p1a + p1b, p2 = p2a + p2b;
        p1 += __shfl_xor(p1, 16); p2 += __shfl_xor(p2, 16);
        p1 += __shfl_xor(p1, 32); p2 += __shfl_xor(p2, 32);

        if (r == 0) {
            float pka = sigf(p1 + tabP1[buf][j]) * tanhf_(p2 + tabP2[buf][j]);
            float hn  = g * h + (1.f - g) * pka;
            float xnv = xn_f[buf][j];        // x_{t+1}
            h_h[j] = (_Float16)hn;
            d_h[j] = (_Float16)(xnv - hn);
            h = hn;
            float pr = xnv * hn;             // y_t product for this column
            pr += __shfl_xor(pr, 1); pr += __shfl_xor(pr, 2);
            pr += __shfl_xor(pr, 4); pr += __shfl_xor(pr, 8);
            if (ln == 0) ypart[wv] = pr;
        }
        // ---- commit step-(t+1) tables into the other buffer ----------------
        {
            const int nb = buf ^ 1;
            if (wv == 0)      *(float2*)&tabCk [nb][2 * ln] = pfNew;
            else if (wv == 1) *(float2*)&tabQk [nb][2 * ln] = pfNew;
            else if (wv == 2) *(float2*)&tabCdk[nb][2 * ln] = pfNew;
            else if (wv == 3) *(float2*)&tabP1 [nb][2 * ln] = pfNew;
            else if (wv == 4) *(float2*)&tabP2 [nb][2 * ln] = pfNew;
        }
        __syncthreads();   // B2
        if (wv == 5) pfHold = pfNew;
    }

    // ---- epilogue: y_510; y[:,511] = 0 --------------------------------------
    if (wv == 6 && ln < 8) {
        float yp = ypart[ln];
        yp += __shfl_xor(yp, 1); yp += __shfl_xor(yp, 2); yp += __shfl_xor(yp, 4);
        if (ln == 0) out[base + 510] = sigf(yp);
    }
    if (tid == 0) out[base + 511] = 0.0f;
}

// ---------------------------------------------------------------------------
extern "C" void kernel_launch(void* const* d_in, const int* in_sizes, int n_in,
                              void* d_out, int out_size, void* d_ws, size_t ws_size,
                              hipStream_t stream) {
    const int*   q_seq    = (const int*)d_in[0];
    const int*   c_seq    = (const int*)d_in[1];
    const int*   qd_seq   = (const int*)d_in[2];
    const int*   cd_seq   = (const int*)d_in[3];
    const int*   corr_seq = (const int*)d_in[4];
    const float* E_q    = (const float*)d_in[5];
    const float* E_c    = (const float*)d_in[6];
    const float* E_qd   = (const float*)d_in[7];
    const float* E_cd   = (const float*)d_in[8];
    const float* E_corr = (const float*)d_in[9];
    const float* Wx     = (const float*)d_in[10];
    const float* bx     = (const float*)d_in[11];
    const float* W_s1   = (const float*)d_in[12];
    const float* b_s1   = (const float*)d_in[13];
    const float* W_s2   = (const float*)d_in[14];
    const float* b_s2   = (const float*)d_in[15];
    const float* W_p1   = (const float*)d_in[16];
    const float* b_p1   = (const float*)d_in[17];
    const float* W_p2   = (const float*)d_in[18];
    const float* b_p2   = (const float*)d_in[19];
    const float* W_ki   = (const float*)d_in[20];
    const float* b_ki   = (const float*)d_in[21];
    const float* h0     = (const float*)d_in[22];
    float* out = (float*)d_out;

    float* xbuf = (float*)d_ws;
    float* Ck   = xbuf + (size_t)BB * SS * DD;
    float* Cp1  = Ck  + 256;
    float* Cp2  = Cp1 + 256;
    float* Qk   = Cp2 + 256;
    float* Cdk  = Qk  + 101 * 128;

    dimkt_tables<<<208, 128, 0, stream>>>(E_corr, E_qd, E_cd, W_ki, W_p1, W_p2,
                                          b_ki, b_p1, b_p2, Ck, Cp1, Cp2, Qk, Cdk);

    dimkt_xgemm<<<(BB * SS) / 128, 256, 0, stream>>>(q_seq, c_seq, qd_seq, cd_seq,
                                                     E_q, E_c, E_qd, E_cd, Wx, bx, xbuf);

    dimkt_scan<<<BB, 512, 0, stream>>>(xbuf, corr_seq, qd_seq, cd_seq,
                                       W_s1, b_s1, W_s2, b_s2, W_p1, W_p2, W_ki,
                                       Ck, Cp1, Cp2, Qk, Cdk, h0, out);
}

// Round 6
// 987.480 us; speedup vs baseline: 1.3698x; 1.1820x over previous
//
#include <hip/hip_runtime.h>

// Problem constants
#define BB 256
#define SS 512
#define DD 128

__device__ __forceinline__ float sigf(float v)  { return 1.0f / (1.0f + __expf(-v)); }
__device__ __forceinline__ float tanhf_(float v){ return 1.0f - 2.0f / (__expf(2.0f * v) + 1.0f); }

typedef _Float16 f16x8 __attribute__((ext_vector_type(8)));
typedef float    f32x4 __attribute__((ext_vector_type(4)));

// ---------------------------------------------------------------------------
// Kernel A: precompute additive tables (fold corr/qd/cd embedding matmul parts)
// ---------------------------------------------------------------------------
__global__ void dimkt_tables(const float* __restrict__ E_corr,
                             const float* __restrict__ E_qd,
                             const float* __restrict__ E_cd,
                             const float* __restrict__ W_ki,
                             const float* __restrict__ W_p1,
                             const float* __restrict__ W_p2,
                             const float* __restrict__ b_ki,
                             const float* __restrict__ b_p1,
                             const float* __restrict__ b_p2,
                             float* __restrict__ Ck, float* __restrict__ Cp1,
                             float* __restrict__ Cp2, float* __restrict__ Qk,
                             float* __restrict__ Cdk)
{
    __shared__ float e[128];
    const int r = blockIdx.x;
    const int j = threadIdx.x;
    const float *emb, *W, *bias;
    float* op;
    if (r < 2)        { emb = E_corr + r * 128;        W = W_ki + 128 * 128; bias = b_ki;    op = Ck  + r * 128; }
    else if (r < 4)   { emb = E_corr + (r - 2) * 128;  W = W_p1 + 128 * 128; bias = b_p1;    op = Cp1 + (r - 2) * 128; }
    else if (r < 6)   { emb = E_corr + (r - 4) * 128;  W = W_p2 + 128 * 128; bias = b_p2;    op = Cp2 + (r - 4) * 128; }
    else if (r < 107) { emb = E_qd   + (r - 6) * 128;  W = W_ki + 256 * 128; bias = nullptr; op = Qk  + (r - 6) * 128; }
    else              { emb = E_cd   + (r - 107) * 128; W = W_ki + 384 * 128; bias = nullptr; op = Cdk + (r - 107) * 128; }
    e[j] = emb[j];
    __syncthreads();
    float acc = bias ? bias[j] : 0.0f;
#pragma unroll 8
    for (int i = 0; i < 128; ++i) acc = fmaf(e[i], W[i * 128 + j], acc);
    op[j] = acc;
}

// ---------------------------------------------------------------------------
// Kernel B: x = concat(E_q[q], E_c[c], E_qd[qd], E_cd[cd]) @ Wx + bx
//   (unchanged — fp32 LDS-tiled GEMM; MFMA candidate next round)
// ---------------------------------------------------------------------------
#define AP 134

__global__ __launch_bounds__(256, 2) void dimkt_xgemm(
    const int* __restrict__ q_seq, const int* __restrict__ c_seq,
    const int* __restrict__ qd_seq, const int* __restrict__ cd_seq,
    const float* __restrict__ E_q, const float* __restrict__ E_c,
    const float* __restrict__ E_qd, const float* __restrict__ E_cd,
    const float* __restrict__ Wx, const float* __restrict__ bx,
    float* __restrict__ xout)
{
    __shared__ float As[128 * AP];
    __shared__ float Bs[128 * 128];
    const int tid = threadIdx.x;
    const int ty = tid >> 4;
    const int tx = tid & 15;
    const int m0 = blockIdx.x * 128;

    const int*   seqs[4] = { q_seq, c_seq, qd_seq, cd_seq };
    const float* tabs[4] = { E_q,   E_c,   E_qd,   E_cd  };

    float acc[8][8];
#pragma unroll
    for (int r = 0; r < 8; ++r)
#pragma unroll
        for (int c = 0; c < 8; ++c) acc[r][c] = 0.0f;

#pragma unroll 1
    for (int s = 0; s < 4; ++s) {
        __syncthreads();
        const int*   sq = seqs[s];
        const float* tb = tabs[s];
        for (int i = tid; i < 128 * 64; i += 256) {
            int row = i >> 6;
            int c2  = (i & 63) << 1;
            int e   = sq[m0 + row];
            float2 v = *(const float2*)&tb[e * 128 + c2];
            *(float2*)&As[row * AP + c2] = v;
        }
        for (int i = tid; i < 128 * 32; i += 256) {
            int k  = i >> 5;
            int c4 = (i & 31) << 2;
            *(float4*)&Bs[k * 128 + c4] = *(const float4*)&Wx[(s * 128 + k) * 128 + c4];
        }
        __syncthreads();
#pragma unroll 4
        for (int k = 0; k < 128; ++k) {
            float a[8];
#pragma unroll
            for (int r = 0; r < 8; ++r) a[r] = As[(ty * 8 + r) * AP + k];
            float4 b0 = *(const float4*)&Bs[k * 128 + tx * 8];
            float4 b1 = *(const float4*)&Bs[k * 128 + tx * 8 + 4];
            float bb[8] = { b0.x, b0.y, b0.z, b0.w, b1.x, b1.y, b1.z, b1.w };
#pragma unroll
            for (int r = 0; r < 8; ++r)
#pragma unroll
                for (int c = 0; c < 8; ++c)
                    acc[r][c] = fmaf(a[r], bb[c], acc[r][c]);
        }
    }

    float4 bx0 = *(const float4*)&bx[tx * 8];
    float4 bx1 = *(const float4*)&bx[tx * 8 + 4];
    float bxa[8] = { bx0.x, bx0.y, bx0.z, bx0.w, bx1.x, bx1.y, bx1.z, bx1.w };
#pragma unroll
    for (int r = 0; r < 8; ++r) {
        int row = m0 + ty * 8 + r;
        float4 o0 = make_float4(acc[r][0] + bxa[0], acc[r][1] + bxa[1],
                                acc[r][2] + bxa[2], acc[r][3] + bxa[3]);
        float4 o1 = make_float4(acc[r][4] + bxa[4], acc[r][5] + bxa[5],
                                acc[r][6] + bxa[6], acc[r][7] + bxa[7]);
        *(float4*)&xout[row * 128 + tx * 8]     = o0;
        *(float4*)&xout[row * 128 + tx * 8 + 4] = o1;
    }
}

// ---------------------------------------------------------------------------
// helper: load one B-fragment of a weight matrix (16x16x32 f16 MFMA).
// lane l of a wave holds W[kbase + e][j] for e=0..7, where kbase already
// includes kf*32 + (l>>4)*8. Natural row-major W — no transpose needed.
// ---------------------------------------------------------------------------
__device__ __forceinline__ f16x8 load_wfrag(const float* __restrict__ W,
                                            int kbase, int j) {
    f16x8 r;
#pragma unroll
    for (int e = 0; e < 8; ++e) r[e] = (_Float16)W[(kbase + e) * DD + j];
    return r;
}

#define MFMA16(A, B, C) __builtin_amdgcn_mfma_f32_16x16x32_f16((A), (B), (C), 0, 0, 0)

// ---------------------------------------------------------------------------
// Kernel C: sequential scan, v5 — matvecs on the MFMA pipe.
//   512 threads (8 waves, 2/SIMD), 1 block per batch element.
//   Wave wv owns output cols [16wv, 16wv+16). Per matvec y = v @ W:
//     A-frag = v replicated across all 16 rows (lane reads depend only on
//              l>>4, so rows are identical -> every lane's C regs hold the
//              full result for its column l&15),
//     B-frag = W in natural row-major (k = kf*32 + (l>>4)*8 + e).
//   K-reduction happens inside MFMA (no shfl chains); weights live in 20
//   named fragments — AGPR demotion is harmless since MFMA reads AGPRs.
//   2 barriers/step. Per-wave table/x loads = exactly its 16-col slice.
// ---------------------------------------------------------------------------
__global__ __launch_bounds__(512, 2) void dimkt_scan(
    const float* __restrict__ x,
    const int* __restrict__ corr_seq, const int* __restrict__ qd_seq,
    const int* __restrict__ cd_seq,
    const float* __restrict__ W_s1, const float* __restrict__ b_s1,
    const float* __restrict__ W_s2, const float* __restrict__ b_s2,
    const float* __restrict__ W_p1, const float* __restrict__ W_p2,
    const float* __restrict__ W_ki,
    const float* __restrict__ Ck, const float* __restrict__ Cp1,
    const float* __restrict__ Cp2, const float* __restrict__ Qk,
    const float* __restrict__ Cdk,
    const float* __restrict__ h0, float* __restrict__ out)
{
    __shared__ __align__(16) _Float16 d_h[128];
    __shared__ __align__(16) _Float16 h_h[128];
    __shared__ __align__(16) _Float16 s_h[128];
    __shared__ float ypart[8];

    const int tid  = threadIdx.x;
    const int b    = blockIdx.x;
    const int wv   = tid >> 6;        // wave 0..7: cols [16wv, 16wv+16)
    const int l    = tid & 63;
    const int kgrp = l >> 4;          // k-group 0..3 within a fragment
    const int j    = wv * 16 + (l & 15);
    const int base = b * SS;

    // --- 20 named weight B-fragments (4 k-frags x 5 matrices) ---------------
    const int kb = kgrp * 8;
    const f16x8 w1f0 = load_wfrag(W_s1,  0 + kb, j);
    const f16x8 w1f1 = load_wfrag(W_s1, 32 + kb, j);
    const f16x8 w1f2 = load_wfrag(W_s1, 64 + kb, j);
    const f16x8 w1f3 = load_wfrag(W_s1, 96 + kb, j);
    const f16x8 w2f0 = load_wfrag(W_s2,  0 + kb, j);
    const f16x8 w2f1 = load_wfrag(W_s2, 32 + kb, j);
    const f16x8 w2f2 = load_wfrag(W_s2, 64 + kb, j);
    const f16x8 w2f3 = load_wfrag(W_s2, 96 + kb, j);
    const f16x8 wkf0 = load_wfrag(W_ki,  0 + kb, j);
    const f16x8 wkf1 = load_wfrag(W_ki, 32 + kb, j);
    const f16x8 wkf2 = load_wfrag(W_ki, 64 + kb, j);
    const f16x8 wkf3 = load_wfrag(W_ki, 96 + kb, j);
    const f16x8 p1f0 = load_wfrag(W_p1,  0 + kb, j);
    const f16x8 p1f1 = load_wfrag(W_p1, 32 + kb, j);
    const f16x8 p1f2 = load_wfrag(W_p1, 64 + kb, j);
    const f16x8 p1f3 = load_wfrag(W_p1, 96 + kb, j);
    const f16x8 p2f0 = load_wfrag(W_p2,  0 + kb, j);
    const f16x8 p2f1 = load_wfrag(W_p2, 32 + kb, j);
    const f16x8 p2f2 = load_wfrag(W_p2, 64 + kb, j);
    const f16x8 p2f3 = load_wfrag(W_p2, 96 + kb, j);

    // --- init ---------------------------------------------------------------
    const float bs1 = b_s1[j];
    const float bs2 = b_s2[j];
    float h  = h0[b * DD + j];
    float x0 = x[(size_t)base * DD + j];
    if (kgrp == 0) {
        h_h[j] = (_Float16)h;
        d_h[j] = (_Float16)(x0 - h);
    }
    // step-0 tables (per-wave 16-col slices), x_1 prefetch
    int ic0 = corr_seq[base], iq0 = qd_seq[base], ie0 = cd_seq[base];
    float tck = Ck [ic0 * DD + j];
    float tqk = Qk [iq0 * DD + j];
    float tcd = Cdk[ie0 * DD + j];
    float tp1 = Cp1[ic0 * DD + j];
    float tp2 = Cp2[ic0 * DD + j];
    float xn  = x[(size_t)(base + 1) * DD + j];
    __syncthreads();

    for (int t = 0; t < 511; ++t) {
        // ---- prefetch step-(t+1) tables and x_{t+2} ------------------------
        const int n1 = base + t + 1;
        int ic = corr_seq[n1], iq = qd_seq[n1], ie = cd_seq[n1];
        float nck = Ck [ic * DD + j];
        float nqk = Qk [iq * DD + j];
        float ncd = Cdk[ie * DD + j];
        float np1 = Cp1[ic * DD + j];
        float np2 = Cp2[ic * DD + j];
        int xp = (t + 2 > 511) ? 511 : (t + 2);
        float xnn = x[(size_t)(base + xp) * DD + j];

        // ---- wave0 side-job: emit y_{t-1} (ypart written before last B2) ---
        if (wv == 0 && l < 8 && t > 0) {
            float yp = ypart[l];
            yp += __shfl_xor(yp, 1); yp += __shfl_xor(yp, 2); yp += __shfl_xor(yp, 4);
            if (l == 0) out[base + t - 1] = sigf(yp);
        }

        // ---- phase 1: a1 = d@Ws1, a2 = d@Ws2, kg = h@Wki_h ------------------
        // A-frags: vector replicated across rows (address depends only on kgrp)
        const f16x8 dA0 = *(const f16x8*)&d_h[ 0 + kb];
        const f16x8 dA1 = *(const f16x8*)&d_h[32 + kb];
        const f16x8 dA2 = *(const f16x8*)&d_h[64 + kb];
        const f16x8 dA3 = *(const f16x8*)&d_h[96 + kb];
        const f16x8 hA0 = *(const f16x8*)&h_h[ 0 + kb];
        const f16x8 hA1 = *(const f16x8*)&h_h[32 + kb];
        const f16x8 hA2 = *(const f16x8*)&h_h[64 + kb];
        const f16x8 hA3 = *(const f16x8*)&h_h[96 + kb];

        f32x4 c1 = {0.f, 0.f, 0.f, 0.f};
        f32x4 c2 = {0.f, 0.f, 0.f, 0.f};
        f32x4 ckg = {0.f, 0.f, 0.f, 0.f};
        c1  = MFMA16(dA0, w1f0, c1);  c2  = MFMA16(dA0, w2f0, c2);  ckg = MFMA16(hA0, wkf0, ckg);
        c1  = MFMA16(dA1, w1f1, c1);  c2  = MFMA16(dA1, w2f1, c2);  ckg = MFMA16(hA1, wkf1, ckg);
        c1  = MFMA16(dA2, w1f2, c1);  c2  = MFMA16(dA2, w2f2, c2);  ckg = MFMA16(hA2, wkf2, ckg);
        c1  = MFMA16(dA3, w1f3, c1);  c2  = MFMA16(dA3, w2f3, c2);  ckg = MFMA16(hA3, wkf3, ckg);

        // every lane holds the full result for its column (C rows identical)
        float sdf = sigf(c1[0] + bs1) * tanhf_(c2[0] + bs2);
        float g   = sigf(ckg[0] + tck + tqk + tcd);
        if (kgrp == 0) s_h[j] = (_Float16)sdf;
        __syncthreads();   // B1

        // ---- phase 2: p1 = sdf@Wp1_h, p2 = sdf@Wp2_h; h update -------------
        const f16x8 sA0 = *(const f16x8*)&s_h[ 0 + kb];
        const f16x8 sA1 = *(const f16x8*)&s_h[32 + kb];
        const f16x8 sA2 = *(const f16x8*)&s_h[64 + kb];
        const f16x8 sA3 = *(const f16x8*)&s_h[96 + kb];

        f32x4 cp1 = {0.f, 0.f, 0.f, 0.f};
        f32x4 cp2 = {0.f, 0.f, 0.f, 0.f};
        cp1 = MFMA16(sA0, p1f0, cp1);  cp2 = MFMA16(sA0, p2f0, cp2);
        cp1 = MFMA16(sA1, p1f1, cp1);  cp2 = MFMA16(sA1, p2f1, cp2);
        cp1 = MFMA16(sA2, p1f2, cp1);  cp2 = MFMA16(sA2, p2f2, cp2);
        cp1 = MFMA16(sA3, p1f3, cp1);  cp2 = MFMA16(sA3, p2f3, cp2);

        float pka = sigf(cp1[0] + tp1) * tanhf_(cp2[0] + tp2);
        float hn  = g * h + (1.f - g) * pka;
        float dn  = xn - hn;             // d for step t+1
        float pr  = xn * hn;             // y_t product for this column
        if (kgrp == 0) {
            h_h[j] = (_Float16)hn;
            d_h[j] = (_Float16)dn;
        }
        // per-wave y partial: sum over the wave's 16 cols (replicated groups)
        pr += __shfl_xor(pr, 1); pr += __shfl_xor(pr, 2);
        pr += __shfl_xor(pr, 4); pr += __shfl_xor(pr, 8);
        if (l == 0) ypart[wv] = pr;

        h = hn; xn = xnn;
        tck = nck; tqk = nqk; tcd = ncd; tp1 = np1; tp2 = np2;
        __syncthreads();   // B2
    }

    // ---- epilogue: y_510; y[:,511] = 0 --------------------------------------
    if (wv == 0 && l < 8) {
        float yp = ypart[l];
        yp += __shfl_xor(yp, 1); yp += __shfl_xor(yp, 2); yp += __shfl_xor(yp, 4);
        if (l == 0) out[base + 510] = sigf(yp);
    }
    if (tid == 0) out[base + 511] = 0.0f;
}

// ---------------------------------------------------------------------------
extern "C" void kernel_launch(void* const* d_in, const int* in_sizes, int n_in,
                              void* d_out, int out_size, void* d_ws, size_t ws_size,
                              hipStream_t stream) {
    const int*   q_seq    = (const int*)d_in[0];
    const int*   c_seq    = (const int*)d_in[1];
    const int*   qd_seq   = (const int*)d_in[2];
    const int*   cd_seq   = (const int*)d_in[3];
    const int*   corr_seq = (const int*)d_in[4];
    const float* E_q    = (const float*)d_in[5];
    const float* E_c    = (const float*)d_in[6];
    const float* E_qd   = (const float*)d_in[7];
    const float* E_cd   = (const float*)d_in[8];
    const float* E_corr = (const float*)d_in[9];
    const float* Wx     = (const float*)d_in[10];
    const float* bx     = (const float*)d_in[11];
    const float* W_s1   = (const float*)d_in[12];
    const float* b_s1   = (const float*)d_in[13];
    const float* W_s2   = (const float*)d_in[14];
    const float* b_s2   = (const float*)d_in[15];
    const float* W_p1   = (const float*)d_in[16];
    const float* b_p1   = (const float*)d_in[17];
    const float* W_p2   = (const float*)d_in[18];
    const float* b_p2   = (const float*)d_in[19];
    const float* W_ki   = (const float*)d_in[20];
    const float* b_ki   = (const float*)d_in[21];
    const float* h0     = (const float*)d_in[22];
    float* out = (float*)d_out;

    float* xbuf = (float*)d_ws;
    float* Ck   = xbuf + (size_t)BB * SS * DD;
    float* Cp1  = Ck  + 256;
    float* Cp2  = Cp1 + 256;
    float* Qk   = Cp2 + 256;
    float* Cdk  = Qk  + 101 * 128;

    dimkt_tables<<<208, 128, 0, stream>>>(E_corr, E_qd, E_cd, W_ki, W_p1, W_p2,
                                          b_ki, b_p1, b_p2, Ck, Cp1, Cp2, Qk, Cdk);

    dimkt_xgemm<<<(BB * SS) / 128, 256, 0, stream>>>(q_seq, c_seq, qd_seq, cd_seq,
                                                     E_q, E_c, E_qd, E_cd, Wx, bx, xbuf);

    dimkt_scan<<<BB, 512, 0, stream>>>(xbuf, corr_seq, qd_seq, cd_seq,
                                       W_s1, b_s1, W_s2, b_s2, W_p1, W_p2, W_ki,
                                       Ck, Cp1, Cp2, Qk, Cdk, h0, out);
}

// Round 7
// 521.069 us; speedup vs baseline: 2.5959x; 1.8951x over previous
//
#include <hip/hip_runtime.h>

// Problem constants
#define BB 256
#define SS 512
#define DD 128

// fast sigmoid/tanh via v_rcp_f32 (approx rcp, ~1ulp) — avoids IEEE division
__device__ __forceinline__ float sigf(float v) {
    return __builtin_amdgcn_rcpf(1.0f + __expf(-v));
}
__device__ __forceinline__ float tanhf_(float v) {
    return 1.0f - 2.0f * __builtin_amdgcn_rcpf(__expf(2.0f * v) + 1.0f);
}

typedef _Float16 f16x2 __attribute__((ext_vector_type(2)));
typedef _Float16 f16x8 __attribute__((ext_vector_type(8)));
typedef float    f32x4 __attribute__((ext_vector_type(4)));

#define MFMA16(A, B, C) __builtin_amdgcn_mfma_f32_16x16x32_f16((A), (B), (C), 0, 0, 0)

// ---------------------------------------------------------------------------
// Kernel P: convert embedding tables + Wx to f16 (Wx transposed to [n][k]).
// ---------------------------------------------------------------------------
#define N_EQ  (20000 * 128)
#define N_EC  (2000 * 128)
#define N_EQD (101 * 128)
#define N_ECD (101 * 128)
#define N_WXT (512 * 128)
#define N_CVT (N_EQ + N_EC + N_EQD + N_ECD + N_WXT)

__global__ __launch_bounds__(256) void dimkt_cvt(
    const float* __restrict__ E_q, const float* __restrict__ E_c,
    const float* __restrict__ E_qd, const float* __restrict__ E_cd,
    const float* __restrict__ Wx,
    _Float16* __restrict__ E_qh, _Float16* __restrict__ E_ch,
    _Float16* __restrict__ E_qdh, _Float16* __restrict__ E_cdh,
    _Float16* __restrict__ WxTh)
{
    int o = blockIdx.x * 256 + threadIdx.x;
    if (o >= N_CVT) return;
    if (o < N_EQ) { E_qh[o] = (_Float16)E_q[o]; return; }
    o -= N_EQ;
    if (o < N_EC) { E_ch[o] = (_Float16)E_c[o]; return; }
    o -= N_EC;
    if (o < N_EQD) { E_qdh[o] = (_Float16)E_qd[o]; return; }
    o -= N_EQD;
    if (o < N_ECD) { E_cdh[o] = (_Float16)E_cd[o]; return; }
    o -= N_ECD;
    int n = o >> 9, k = o & 511;                 // WxTh[n][k] = Wx[k][n]
    WxTh[o] = (_Float16)Wx[k * 128 + n];
}

// ---------------------------------------------------------------------------
// Kernel A: precompute additive tables (fold corr/qd/cd embedding matmul parts)
// ---------------------------------------------------------------------------
__global__ void dimkt_tables(const float* __restrict__ E_corr,
                             const float* __restrict__ E_qd,
                             const float* __restrict__ E_cd,
                             const float* __restrict__ W_ki,
                             const float* __restrict__ W_p1,
                             const float* __restrict__ W_p2,
                             const float* __restrict__ b_ki,
                             const float* __restrict__ b_p1,
                             const float* __restrict__ b_p2,
                             float* __restrict__ Ck, float* __restrict__ Cp1,
                             float* __restrict__ Cp2, float* __restrict__ Qk,
                             float* __restrict__ Cdk)
{
    __shared__ float e[128];
    const int r = blockIdx.x;
    const int j = threadIdx.x;
    const float *emb, *W, *bias;
    float* op;
    if (r < 2)        { emb = E_corr + r * 128;        W = W_ki + 128 * 128; bias = b_ki;    op = Ck  + r * 128; }
    else if (r < 4)   { emb = E_corr + (r - 2) * 128;  W = W_p1 + 128 * 128; bias = b_p1;    op = Cp1 + (r - 2) * 128; }
    else if (r < 6)   { emb = E_corr + (r - 4) * 128;  W = W_p2 + 128 * 128; bias = b_p2;    op = Cp2 + (r - 4) * 128; }
    else if (r < 107) { emb = E_qd   + (r - 6) * 128;  W = W_ki + 256 * 128; bias = nullptr; op = Qk  + (r - 6) * 128; }
    else              { emb = E_cd   + (r - 107) * 128; W = W_ki + 384 * 128; bias = nullptr; op = Cdk + (r - 107) * 128; }
    e[j] = emb[j];
    __syncthreads();
    float acc = bias ? bias[j] : 0.0f;
#pragma unroll 8
    for (int i = 0; i < 128; ++i) acc = fmaf(e[i], W[i * 128 + j], acc);
    op[j] = acc;
}

// ---------------------------------------------------------------------------
// Kernel B v2: x = concat-gather @ Wx + bx via f16 MFMA. No LDS, no barriers.
//   1024 blocks x 256 threads (4 waves). Wave wv owns rows [m0+32wv, +32)
//   (2 rowfrags) x all 128 cols (8 colfrags). B-frags straight from the
//   L2-resident transposed WxTh[n][k] (16B/lane contiguous); A-frags gathered
//   16B/lane from f16 embedding tables. 256 MFMA / wave.
//   Fragment mapping (same as the verified scan kernel's B usage, applied
//   symmetrically): A row / B col = l&15, k = (l>>4)*8 + e.
//   C mapping: col = l&15, row = (l>>4)*4 + reg  [guide m89].
// ---------------------------------------------------------------------------
__global__ __launch_bounds__(256, 2) void dimkt_xgemm(
    const int* __restrict__ q_seq, const int* __restrict__ c_seq,
    const int* __restrict__ qd_seq, const int* __restrict__ cd_seq,
    const _Float16* __restrict__ E_qh, const _Float16* __restrict__ E_ch,
    const _Float16* __restrict__ E_qdh, const _Float16* __restrict__ E_cdh,
    const _Float16* __restrict__ WxTh,
    const float* __restrict__ bx, float* __restrict__ xout)
{
    const int tid = threadIdx.x;
    const int wv  = tid >> 6;          // wave 0..3
    const int l   = tid & 63;
    const int lm  = l & 15;
    const int kg8 = (l >> 4) * 8;
    const int m0  = blockIdx.x * 128;
    const int rbase = m0 + wv * 32;

    f32x4 acc0[8], acc1[8];
#pragma unroll
    for (int c = 0; c < 8; ++c) {
        acc0[c] = (f32x4){0.f, 0.f, 0.f, 0.f};
        acc1[c] = (f32x4){0.f, 0.f, 0.f, 0.f};
    }

#pragma unroll
    for (int s = 0; s < 4; ++s) {
        const _Float16* T  = (s == 0) ? E_qh : (s == 1) ? E_ch : (s == 2) ? E_qdh : E_cdh;
        const int*      sq = (s == 0) ? q_seq : (s == 1) ? c_seq : (s == 2) ? qd_seq : cd_seq;
        const int i0 = sq[rbase + lm];
        const int i1 = sq[rbase + 16 + lm];
        const _Float16* a0p = T + (size_t)i0 * 128 + kg8;
        const _Float16* a1p = T + (size_t)i1 * 128 + kg8;
#pragma unroll
        for (int kk = 0; kk < 4; ++kk) {
            const f16x8 a0 = *(const f16x8*)(a0p + kk * 32);
            const f16x8 a1 = *(const f16x8*)(a1p + kk * 32);
#pragma unroll
            for (int c = 0; c < 8; ++c) {
                const f16x8 bf = *(const f16x8*)&WxTh[(size_t)(c * 16 + lm) * 512
                                                      + s * 128 + kk * 32 + kg8];
                acc0[c] = MFMA16(a0, bf, acc0[c]);
                acc1[c] = MFMA16(a1, bf, acc1[c]);
            }
        }
    }

    // epilogue: + bx, store (C: col = l&15, row = 4*(l>>4)+r)
#pragma unroll
    for (int c = 0; c < 8; ++c) {
        const int col = c * 16 + lm;
        const float bxv = bx[col];
#pragma unroll
        for (int r = 0; r < 4; ++r) {
            const int row0 = rbase + (l >> 4) * 4 + r;
            xout[(size_t)row0 * 128 + col]        = acc0[c][r] + bxv;
            xout[(size_t)(row0 + 16) * 128 + col] = acc1[c][r] + bxv;
        }
    }
}

// ---------------------------------------------------------------------------
// helper: load one B-fragment of a weight matrix (16x16x32 f16 MFMA).
// ---------------------------------------------------------------------------
__device__ __forceinline__ f16x8 load_wfrag(const float* __restrict__ W,
                                            int kbase, int j) {
    f16x8 r;
#pragma unroll
    for (int e = 0; e < 8; ++e) r[e] = (_Float16)W[(kbase + e) * DD + j];
    return r;
}

// ---------------------------------------------------------------------------
// Kernel C: sequential scan, v6 (r6 + fixes).
//   - rcp-based sigmoid/tanh (r6: IEEE division = ~60 VALU/step extra)
//   - indices pipelined 2 steps ahead (r6: idx->table serial chain ~400cy)
//   - y moved OUT of the scan: h_{t+1} stored f16 to hbuf; y computed by
//     dimkt_y afterwards (r6: 4-deep shfl chain + wave0 divergence)
//   - MFMA chains split 2-deep (we only consume C[0]; join = 1 scalar add)
// ---------------------------------------------------------------------------
__global__ __launch_bounds__(512, 2) void dimkt_scan(
    const float* __restrict__ x,
    const int* __restrict__ corr_seq, const int* __restrict__ qd_seq,
    const int* __restrict__ cd_seq,
    const float* __restrict__ W_s1, const float* __restrict__ b_s1,
    const float* __restrict__ W_s2, const float* __restrict__ b_s2,
    const float* __restrict__ W_p1, const float* __restrict__ W_p2,
    const float* __restrict__ W_ki,
    const float* __restrict__ Ck, const float* __restrict__ Cp1,
    const float* __restrict__ Cp2, const float* __restrict__ Qk,
    const float* __restrict__ Cdk,
    const float* __restrict__ h0, _Float16* __restrict__ hb,
    float* __restrict__ out)
{
    __shared__ __align__(16) _Float16 d_h[128];
    __shared__ __align__(16) _Float16 h_h[128];
    __shared__ __align__(16) _Float16 s_h[128];

    const int tid  = threadIdx.x;
    const int b    = blockIdx.x;
    const int wv   = tid >> 6;        // wave 0..7: cols [16wv, 16wv+16)
    const int l    = tid & 63;
    const int kgrp = l >> 4;          // k-group 0..3 within a fragment
    const int j    = wv * 16 + (l & 15);
    const int base = b * SS;

    // --- 20 named weight B-fragments (4 k-frags x 5 matrices) ---------------
    const int kb = kgrp * 8;
    const f16x8 w1f0 = load_wfrag(W_s1,  0 + kb, j);
    const f16x8 w1f1 = load_wfrag(W_s1, 32 + kb, j);
    const f16x8 w1f2 = load_wfrag(W_s1, 64 + kb, j);
    const f16x8 w1f3 = load_wfrag(W_s1, 96 + kb, j);
    const f16x8 w2f0 = load_wfrag(W_s2,  0 + kb, j);
    const f16x8 w2f1 = load_wfrag(W_s2, 32 + kb, j);
    const f16x8 w2f2 = load_wfrag(W_s2, 64 + kb, j);
    const f16x8 w2f3 = load_wfrag(W_s2, 96 + kb, j);
    const f16x8 wkf0 = load_wfrag(W_ki,  0 + kb, j);
    const f16x8 wkf1 = load_wfrag(W_ki, 32 + kb, j);
    const f16x8 wkf2 = load_wfrag(W_ki, 64 + kb, j);
    const f16x8 wkf3 = load_wfrag(W_ki, 96 + kb, j);
    const f16x8 p1f0 = load_wfrag(W_p1,  0 + kb, j);
    const f16x8 p1f1 = load_wfrag(W_p1, 32 + kb, j);
    const f16x8 p1f2 = load_wfrag(W_p1, 64 + kb, j);
    const f16x8 p1f3 = load_wfrag(W_p1, 96 + kb, j);
    const f16x8 p2f0 = load_wfrag(W_p2,  0 + kb, j);
    const f16x8 p2f1 = load_wfrag(W_p2, 32 + kb, j);
    const f16x8 p2f2 = load_wfrag(W_p2, 64 + kb, j);
    const f16x8 p2f3 = load_wfrag(W_p2, 96 + kb, j);

    // --- init ---------------------------------------------------------------
    const float bs1 = b_s1[j];
    const float bs2 = b_s2[j];
    float h  = h0[b * DD + j];
    float x0 = x[(size_t)base * DD + j];
    if (kgrp == 0) {
        h_h[j] = (_Float16)h;
        d_h[j] = (_Float16)(x0 - h);
    }
    // step-0 tables (serial chain, prologue only)
    {
        int ic0 = corr_seq[base], iq0 = qd_seq[base], ie0 = cd_seq[base];
        // nothing else depends on these before first use
        float a = Ck [ic0 * DD + j];  float q = Qk [iq0 * DD + j];
        float c = Cdk[ie0 * DD + j];  float p = Cp1[ic0 * DD + j];
        float p2v = Cp2[ic0 * DD + j];
        // current-step table regs
        // (assigned below to avoid shadowing)
        // fallthrough
        // indices for step 1 (consumed next iteration's table loads)
        // loaded AFTER the table loads so they overlap
        // ---
        // assign
        // (kept verbose for clarity)
        // current tables:
        // tck..tp2
        // next-step indices:
        // icN..ieN
        // x prefetch
        // xn
        // all below
        // ---
        // (single basic block; compiler schedules loads early)
        // ---
        // store into the named registers:
        // (see below)
        // ---
        // NOTE: code continues outside this brace
        // to keep variables in scope we re-declare outside
        (void)a; (void)q; (void)c; (void)p; (void)p2v;
    }
    int ic0 = corr_seq[base], iq0 = qd_seq[base], ie0 = cd_seq[base];
    float tck = Ck [ic0 * DD + j];
    float tqk = Qk [iq0 * DD + j];
    float tcd = Cdk[ie0 * DD + j];
    float tp1 = Cp1[ic0 * DD + j];
    float tp2 = Cp2[ic0 * DD + j];
    // indices for step t+1 (pipelined one step ahead of their table loads)
    int icN = corr_seq[base + 1], iqN = qd_seq[base + 1], ieN = cd_seq[base + 1];
    float xn  = x[(size_t)(base + 1) * DD + j];
    __syncthreads();

    for (int t = 0; t < 511; ++t) {
        // ---- prefetch: tables(t+1) from pipelined indices; indices(t+2);
        //      x_{t+2} — all independent, no serial chain ------------------
        float nck = Ck [icN * DD + j];
        float nqk = Qk [iqN * DD + j];
        float ncd = Cdk[ieN * DD + j];
        float np1 = Cp1[icN * DD + j];
        float np2 = Cp2[icN * DD + j];
        const int n2 = base + ((t + 2 > 511) ? 511 : (t + 2));
        int icN2 = corr_seq[n2], iqN2 = qd_seq[n2], ieN2 = cd_seq[n2];
        int xp = (t + 2 > 511) ? 511 : (t + 2);
        float xnn = x[(size_t)(base + xp) * DD + j];

        // ---- phase 1: a1 = d@Ws1, a2 = d@Ws2, kg = h@Wki_h ------------------
        const f16x8 dA0 = *(const f16x8*)&d_h[ 0 + kb];
        const f16x8 dA1 = *(const f16x8*)&d_h[32 + kb];
        const f16x8 dA2 = *(const f16x8*)&d_h[64 + kb];
        const f16x8 dA3 = *(const f16x8*)&d_h[96 + kb];
        const f16x8 hA0 = *(const f16x8*)&h_h[ 0 + kb];
        const f16x8 hA1 = *(const f16x8*)&h_h[32 + kb];
        const f16x8 hA2 = *(const f16x8*)&h_h[64 + kb];
        const f16x8 hA3 = *(const f16x8*)&h_h[96 + kb];

        const f32x4 z = {0.f, 0.f, 0.f, 0.f};
        f32x4 c1a = MFMA16(dA0, w1f0, z);
        f32x4 c2a = MFMA16(dA0, w2f0, z);
        f32x4 cka = MFMA16(hA0, wkf0, z);
        f32x4 c1b = MFMA16(dA2, w1f2, z);
        f32x4 c2b = MFMA16(dA2, w2f2, z);
        f32x4 ckb = MFMA16(hA2, wkf2, z);
        c1a = MFMA16(dA1, w1f1, c1a);
        c2a = MFMA16(dA1, w2f1, c2a);
        cka = MFMA16(hA1, wkf1, cka);
        c1b = MFMA16(dA3, w1f3, c1b);
        c2b = MFMA16(dA3, w2f3, c2b);
        ckb = MFMA16(hA3, wkf3, ckb);

        float sdf = sigf(c1a[0] + c1b[0] + bs1) * tanhf_(c2a[0] + c2b[0] + bs2);
        float g   = sigf(cka[0] + ckb[0] + tck + tqk + tcd);
        if (kgrp == 0) s_h[j] = (_Float16)sdf;
        __syncthreads();   // B1

        // ---- phase 2: p1 = sdf@Wp1_h, p2 = sdf@Wp2_h; h update -------------
        const f16x8 sA0 = *(const f16x8*)&s_h[ 0 + kb];
        const f16x8 sA1 = *(const f16x8*)&s_h[32 + kb];
        const f16x8 sA2 = *(const f16x8*)&s_h[64 + kb];
        const f16x8 sA3 = *(const f16x8*)&s_h[96 + kb];

        f32x4 q1a = MFMA16(sA0, p1f0, z);
        f32x4 q2a = MFMA16(sA0, p2f0, z);
        f32x4 q1b = MFMA16(sA2, p1f2, z);
        f32x4 q2b = MFMA16(sA2, p2f2, z);
        q1a = MFMA16(sA1, p1f1, q1a);
        q2a = MFMA16(sA1, p2f1, q2a);
        q1b = MFMA16(sA3, p1f3, q1b);
        q2b = MFMA16(sA3, p2f3, q2b);

        float pka = sigf(q1a[0] + q1b[0] + tp1) * tanhf_(q2a[0] + q2b[0] + tp2);
        float hn  = g * h + (1.f - g) * pka;
        _Float16 hn16 = (_Float16)hn;
        if (kgrp == 0) {
            h_h[j] = hn16;
            d_h[j] = (_Float16)(xn - hn);
            hb[(size_t)(base + t) * DD + j] = hn16;   // h_{t+1} for y-kernel
        }

        h = hn; xn = xnn;
        tck = nck; tqk = nqk; tcd = ncd; tp1 = np1; tp2 = np2;
        icN = icN2; iqN = iqN2; ieN = ieN2;
        __syncthreads();   // B2
    }

    if (tid == 0) out[base + 511] = 0.0f;
}

// ---------------------------------------------------------------------------
// Kernel D: y[b][t] = sigmoid(dot(x[b][t+1], h_{t+1})), t = 0..510.
//   One wave per output; memory-bound (~100 MB).
// ---------------------------------------------------------------------------
__global__ __launch_bounds__(256) void dimkt_y(
    const float* __restrict__ x, const _Float16* __restrict__ hb,
    float* __restrict__ out)
{
    const int o = blockIdx.x * 4 + (threadIdx.x >> 6);   // flat (b,t)
    const int l = threadIdx.x & 63;
    const int b = o >> 9;
    const int t = o & 511;
    if (t == 511) return;   // handled by scan
    float2 xv = *(const float2*)&x[((size_t)(b * SS + t + 1)) * DD + 2 * l];
    f16x2  hv = *(const f16x2*)&hb[((size_t)(b * SS + t)) * DD + 2 * l];
    float s = xv.x * (float)hv.x + xv.y * (float)hv.y;
    s += __shfl_xor(s, 1);  s += __shfl_xor(s, 2);  s += __shfl_xor(s, 4);
    s += __shfl_xor(s, 8);  s += __shfl_xor(s, 16); s += __shfl_xor(s, 32);
    if (l == 0) out[b * SS + t] = sigf(s);
}

// ---------------------------------------------------------------------------
extern "C" void kernel_launch(void* const* d_in, const int* in_sizes, int n_in,
                              void* d_out, int out_size, void* d_ws, size_t ws_size,
                              hipStream_t stream) {
    const int*   q_seq    = (const int*)d_in[0];
    const int*   c_seq    = (const int*)d_in[1];
    const int*   qd_seq   = (const int*)d_in[2];
    const int*   cd_seq   = (const int*)d_in[3];
    const int*   corr_seq = (const int*)d_in[4];
    const float* E_q    = (const float*)d_in[5];
    const float* E_c    = (const float*)d_in[6];
    const float* E_qd   = (const float*)d_in[7];
    const float* E_cd   = (const float*)d_in[8];
    const float* E_corr = (const float*)d_in[9];
    const float* Wx     = (const float*)d_in[10];
    const float* bx     = (const float*)d_in[11];
    const float* W_s1   = (const float*)d_in[12];
    const float* b_s1   = (const float*)d_in[13];
    const float* W_s2   = (const float*)d_in[14];
    const float* b_s2   = (const float*)d_in[15];
    const float* W_p1   = (const float*)d_in[16];
    const float* b_p1   = (const float*)d_in[17];
    const float* W_p2   = (const float*)d_in[18];
    const float* b_p2   = (const float*)d_in[19];
    const float* W_ki   = (const float*)d_in[20];
    const float* b_ki   = (const float*)d_in[21];
    const float* h0     = (const float*)d_in[22];
    float* out = (float*)d_out;

    // ---- workspace carve-up -------------------------------------------------
    float* xbuf = (float*)d_ws;                       // 16,777,216 f32
    float* Ck   = xbuf + (size_t)BB * SS * DD;        // 2 x 128
    float* Cp1  = Ck  + 256;
    float* Cp2  = Cp1 + 256;
    float* Qk   = Cp2 + 256;                          // 101 x 128
    float* Cdk  = Qk  + 101 * 128;                    // 101 x 128
    // f16 pool starts at f32 offset 16,804,864 (16B aligned)
    _Float16* pool  = (_Float16*)(xbuf + 16804864);
    _Float16* hbuf  = pool;                           // 16,777,216 f16
    _Float16* E_qh  = hbuf + (size_t)BB * SS * DD;    // 20000 x 128
    _Float16* E_ch  = E_qh + N_EQ;                    // 2000 x 128
    _Float16* E_qdh = E_ch + N_EC;                    // 101 x 128
    _Float16* E_cdh = E_qdh + N_EQD;                  // 101 x 128
    _Float16* WxTh  = E_cdh + N_ECD;                  // 128 x 512 (transposed)

    dimkt_cvt<<<(N_CVT + 255) / 256, 256, 0, stream>>>(
        E_q, E_c, E_qd, E_cd, Wx, E_qh, E_ch, E_qdh, E_cdh, WxTh);

    dimkt_tables<<<208, 128, 0, stream>>>(E_corr, E_qd, E_cd, W_ki, W_p1, W_p2,
                                          b_ki, b_p1, b_p2, Ck, Cp1, Cp2, Qk, Cdk);

    dimkt_xgemm<<<(BB * SS) / 128, 256, 0, stream>>>(q_seq, c_seq, qd_seq, cd_seq,
                                                     E_qh, E_ch, E_qdh, E_cdh,
                                                     WxTh, bx, xbuf);

    dimkt_scan<<<BB, 512, 0, stream>>>(xbuf, corr_seq, qd_seq, cd_seq,
                                       W_s1, b_s1, W_s2, b_s2, W_p1, W_p2, W_ki,
                                       Ck, Cp1, Cp2, Qk, Cdk, h0, hbuf, out);

    dimkt_y<<<(BB * SS) / 4, 256, 0, stream>>>(xbuf, hbuf, out);
}